// Round 3
// baseline (3335.581 us; speedup 1.0000x reference)
//
#include <hip/hip_runtime.h>
#include <hip/hip_bf16.h>

#define TT 512
#define BB 32
#define EE 256
#define UU 256
#define NG 1024   // 4*U

typedef unsigned int u32;
typedef unsigned long long u64;
typedef unsigned short u16;
typedef __attribute__((ext_vector_type(8))) short short8;   // 8 bf16 (4 VGPRs)
typedef __attribute__((ext_vector_type(4))) float f32x4;
typedef __attribute__((ext_vector_type(4))) u32 u32x4;

#define TAGMASK 0x0000FFFF0000FFFFull

__device__ __forceinline__ float bf2f(u16 u) { return __uint_as_float(((u32)u) << 16); }
__device__ __forceinline__ u16 f2bf(float f) {
    u32 x = __float_as_uint(f);
    u32 r = (x + 0x7fffu + ((x >> 16) & 1u)) >> 16;   // RNE
    return (u16)r;
}

// ---------------- Phase 1: xw2[dir][t'][ug][b][128] = (emb[tokens] @ Wk + bias), bf16 ----
__launch_bounds__(256)
__global__ void xw_gemm(const int* __restrict__ tokens,
                        const float* __restrict__ emb,
                        const float* __restrict__ Wk_f, const float* __restrict__ b_f,
                        const float* __restrict__ Wk_b, const float* __restrict__ b_b,
                        u16* __restrict__ xw)
{
    const int dir = blockIdx.z;
    const float* Wk   = dir ? Wk_b : Wk_f;
    const float* bias = dir ? b_b  : b_f;
    const int bn = blockIdx.x;   // 8 tiles of 128 cols
    const int bm = blockIdx.y;   // 256 tiles of 64 rows
    const int tid = threadIdx.x;

    __shared__ __align__(16) float At[32][68];
    __shared__ __align__(16) float Bs[32][132];

    float acc[8][4];
#pragma unroll
    for (int i = 0; i < 8; i++)
#pragma unroll
        for (int j = 0; j < 4; j++) acc[i][j] = 0.f;

    const int tx = tid & 31;
    const int ty = tid >> 5;
    const int c0 = tx * 4;
    const int r0 = ty * 8;

    const int lr = tid >> 3;
    const int lk = (tid & 7) * 4;

    for (int k0 = 0; k0 < EE; k0 += 32) {
#pragma unroll
        for (int p = 0; p < 2; p++) {
            int r = lr + p * 32;
            int row = bm * 64 + r;
            int tok = tokens[row];
            const float4 v = *reinterpret_cast<const float4*>(&emb[(size_t)tok * EE + k0 + lk]);
            At[lk + 0][r] = v.x; At[lk + 1][r] = v.y; At[lk + 2][r] = v.z; At[lk + 3][r] = v.w;
        }
        {
            int ck = (tid & 31) * 4;
            int kk = tid >> 5;
#pragma unroll
            for (int p = 0; p < 4; p++) {
                int k = kk + p * 8;
                const float4 v = *reinterpret_cast<const float4*>(&Wk[(size_t)(k0 + k) * NG + bn * 128 + ck]);
                *reinterpret_cast<float4*>(&Bs[k][ck]) = v;
            }
        }
        __syncthreads();
#pragma unroll 8
        for (int k = 0; k < 32; k++) {
            float4 a0 = *reinterpret_cast<const float4*>(&At[k][r0]);
            float4 a1 = *reinterpret_cast<const float4*>(&At[k][r0 + 4]);
            float4 b0 = *reinterpret_cast<const float4*>(&Bs[k][c0]);
            float a[8] = {a0.x, a0.y, a0.z, a0.w, a1.x, a1.y, a1.z, a1.w};
            float b[4] = {b0.x, b0.y, b0.z, b0.w};
#pragma unroll
            for (int i = 0; i < 8; i++)
#pragma unroll
                for (int j = 0; j < 4; j++)
                    acc[i][j] = fmaf(a[i], b[j], acc[i][j]);
        }
        __syncthreads();
    }

    float4 bv = *reinterpret_cast<const float4*>(&bias[bn * 128 + c0]);
    float bias4[4] = {bv.x, bv.y, bv.z, bv.w};
    const int cbase = bn * 128 + c0;
    const int gate  = cbase >> 8;
    const int unitv = cbase & 255;
    const int ugx   = unitv >> 5;
    const int wcol  = gate * 32 + (unitv & 31);
#pragma unroll
    for (int i = 0; i < 8; i++) {
        int row = bm * 64 + r0 + i;
        int b = row >> 9;
        int t = row & 511;
        int t2 = dir ? (TT - 1 - t) : t;
        size_t base = ((((size_t)(dir * TT + t2)) * 8 + ugx) * BB + b) * 128 + wcol;
        ushort4 st;
        st.x = f2bf(acc[i][0] + bias4[0]);
        st.y = f2bf(acc[i][1] + bias4[1]);
        st.z = f2bf(acc[i][2] + bias4[2]);
        st.w = f2bf(acc[i][3] + bias4[3]);
        *reinterpret_cast<ushort4*>(&xw[base]) = st;
    }
}

__device__ __forceinline__ u64 ld_agent(const u64* p) {
    return __hip_atomic_load(p, __ATOMIC_RELAXED, __HIP_MEMORY_SCOPE_AGENT);
}

// ---- sc0 (bypass L1, meet in the XCD's L2) 16x dwordx2 poll, pipelined ----
__device__ __forceinline__ void poll16_l2(u64 b0, u32 voff, u64* q) {
    asm volatile(
        "global_load_dwordx2 %[q0], %[vo], %[b0] sc0\n\t"
        "global_load_dwordx2 %[q1], %[vo], %[b0] offset:512 sc0\n\t"
        "global_load_dwordx2 %[q2], %[vo], %[b0] offset:1024 sc0\n\t"
        "global_load_dwordx2 %[q3], %[vo], %[b0] offset:1536 sc0\n\t"
        "global_load_dwordx2 %[q4], %[vo], %[b0] offset:2048 sc0\n\t"
        "global_load_dwordx2 %[q5], %[vo], %[b0] offset:2560 sc0\n\t"
        "global_load_dwordx2 %[q6], %[vo], %[b0] offset:3072 sc0\n\t"
        "global_load_dwordx2 %[q7], %[vo], %[b0] offset:3584 sc0\n\t"
        "global_load_dwordx2 %[q8], %[vo], %[b1] sc0\n\t"
        "global_load_dwordx2 %[q9], %[vo], %[b1] offset:512 sc0\n\t"
        "global_load_dwordx2 %[q10], %[vo], %[b1] offset:1024 sc0\n\t"
        "global_load_dwordx2 %[q11], %[vo], %[b1] offset:1536 sc0\n\t"
        "global_load_dwordx2 %[q12], %[vo], %[b1] offset:2048 sc0\n\t"
        "global_load_dwordx2 %[q13], %[vo], %[b1] offset:2560 sc0\n\t"
        "global_load_dwordx2 %[q14], %[vo], %[b1] offset:3072 sc0\n\t"
        "global_load_dwordx2 %[q15], %[vo], %[b1] offset:3584 sc0\n\t"
        "s_waitcnt vmcnt(0)"
        : [q0]"=&v"(q[0]), [q1]"=&v"(q[1]), [q2]"=&v"(q[2]), [q3]"=&v"(q[3]),
          [q4]"=&v"(q[4]), [q5]"=&v"(q[5]), [q6]"=&v"(q[6]), [q7]"=&v"(q[7]),
          [q8]"=&v"(q[8]), [q9]"=&v"(q[9]), [q10]"=&v"(q[10]), [q11]"=&v"(q[11]),
          [q12]"=&v"(q[12]), [q13]"=&v"(q[13]), [q14]"=&v"(q[14]), [q15]"=&v"(q[15])
        : [vo]"v"(voff), [b0]"s"(b0), [b1]"s"(b0 + 4096ull)
        : "memory");
}

// Dual-path tagged store: sc0 dwordx4 into this XCD's L2 (fast path) AND the r0-proven
// relaxed agent-scope u64 stores (memory-side, globally visible). Payloads identical,
// tag+data share a u32 -> dword atomicity suffices on both paths.
__device__ __forceinline__ void dual_store(u64* hd, u64 lo, u64 hi) {
    u32x4 v = (u32x4){(u32)lo, (u32)(lo >> 32), (u32)hi, (u32)(hi >> 32)};
    asm volatile("global_store_dwordx4 %[a], %[d], off sc0"
                 :: [a]"v"(hd), [d]"v"(v) : "memory");
    __hip_atomic_store(hd + 0, lo, __ATOMIC_RELAXED, __HIP_MEMORY_SCOPE_AGENT);
    __hip_atomic_store(hd + 1, hi, __ATOMIC_RELAXED, __HIP_MEMORY_SCOPE_AGENT);
}

// ---------------- Phase 2: persistent recurrence, 16 worker WGs clustered on <=2 XCDs ----
// 128 WGs launched; each claims a slot on its physical XCD. First XCD to fill 8 slots
// hosts dir 0; second (or the same XCD's slots 8-15) hosts dir 1; losers exit. Exchange:
// sc0 fast path (XCD L2) with a watchdog fallback to agent-scope (memory-side, r0-proven).
// Every store is dual-path; stuck WGs re-store their last TWO tagged payloads (skew <= 1
// proof => sufficient), so any lost/stale-line update is repaired: fail-to-slow, never hang.
// Tags are epoch-mixed (epoch from s_memrealtime via ctl[2]) so stale lines never match.
__launch_bounds__(256, 1)
__global__ void lstm_rec(const int* __restrict__ tokens,
                         const u16* __restrict__ xw,     // [dir][t][ug][b][128]
                         const float* __restrict__ Wr_f,
                         const float* __restrict__ Wr_b,
                         u64* __restrict__ hgq,          // 2*2*4096 u64 = 256 KB (NOT memset)
                         int* __restrict__ ctl,          // [w0,w1,epoch,pad, cnt[8]] in d_out tail
                         float* __restrict__ out)
{
    const int tid = threadIdx.x;

    __shared__ int s_role, s_epoch;
    __shared__ __align__(16) u32   HsW[32 * 128];   // h as bf16 pairs, swizzled granules (16 KB)
    __shared__ __align__(16) float Zs[2][BB][132];  // parity-buffered z (33.8 KB)

    // ---- XCD claiming (cannot hang: pigeonhole over 128 co-resident WGs sets w0,w1) ----
    if (tid == 0) {
        u32 xcc;
        asm volatile("s_getreg_b32 %0, hwreg(HW_REG_XCC_ID)" : "=s"(xcc));
        xcc &= 7u;
        u32* cnt = (u32*)(ctl + 4);
        u32 slot = atomicAdd(&cnt[xcc], 1u);
        if (slot == 7u) {
            if (atomicCAS(&ctl[0], -1, (int)xcc) == -1) {
                u64 rt = __builtin_amdgcn_s_memrealtime();
                int ep = (int)((((u32)rt ^ (u32)(rt >> 32)) & 0x7FFFFFFEu) | 1u);  // != -1
                atomicExch(&ctl[2], ep);
            } else {
                atomicCAS(&ctl[1], -1, (int)xcc);
            }
        } else if (slot == 15u) {
            atomicCAS(&ctl[1], -1, (int)xcc);
        }
        int w0, w1, ep;
        for (;;) {
            w0 = __hip_atomic_load(&ctl[0], __ATOMIC_RELAXED, __HIP_MEMORY_SCOPE_AGENT);
            w1 = __hip_atomic_load(&ctl[1], __ATOMIC_RELAXED, __HIP_MEMORY_SCOPE_AGENT);
            ep = __hip_atomic_load(&ctl[2], __ATOMIC_RELAXED, __HIP_MEMORY_SCOPE_AGENT);
            if (w0 >= 0 && w1 >= 0 && ep != -1) break;
            __builtin_amdgcn_s_sleep(8);
        }
        int role = -1;
        if ((int)xcc == w0 && slot < 8u) role = (int)slot;                                 // dir 0
        else if (w1 == w0 && (int)xcc == w0 && slot >= 8u && slot < 16u) role = (int)slot; // dir 1 (same XCD)
        else if (w1 != w0 && (int)xcc == w1 && slot < 8u) role = 8 + (int)slot;            // dir 1
        s_role = role;
        s_epoch = ep;
    }
    __syncthreads();
    const int role = s_role;
    const u32 tagbase = (u32)s_epoch * 2654435761u;
    if (role < 0) return;

    const int dir = role >> 3;
    const int ug  = role & 7;
    const int unit0 = ug * 32;
    const int wv  = tid >> 6;        // wave = gate
    const int l   = tid & 63;

    // ---- load Wr B-fragments (bf16) into registers, once ----
    const float* Wr = dir ? Wr_b : Wr_f;
    short8 bfrag[8][2];
    {
        const int col = wv * UU + unit0 + (l & 15);
#pragma unroll
        for (int kt = 0; kt < 8; kt++) {
#pragma unroll
            for (int nt = 0; nt < 2; nt++) {
                int k0 = kt * 32 + (l >> 4) * 8;
                short8 v;
#pragma unroll
                for (int jj = 0; jj < 8; jj++)
                    v[jj] = (short)f2bf(Wr[(size_t)(k0 + jj) * NG + col + nt * 16]);
                bfrag[kt][nt] = v;
            }
        }
    }

    const int cb = tid >> 3;
    const int cj = tid & 7;
    float c_st[4] = {0.f, 0.f, 0.f, 0.f};
    float h_st[4] = {0.f, 0.f, 0.f, 0.f};

    // my exchange slots, both parities (one 128B line per (ug,cb) = one wave: no false sharing)
    u64* const hdP[2] = {
        hgq + (size_t)(0 * 2 + dir) * 4096 + (ug * 32 + cb) * 16 + cj * 2,
        hgq + (size_t)(1 * 2 + dir) * 4096 + (ug * 32 + cb) * 16 + cj * 2
    };
    u64 myLo[2] = {0ull, 0ull}, myHi[2] = {0ull, 0ull};

    // re-store my last two tagged payloads (liveness repair; skew<=1 => sufficient)
    auto restoreMine = [&](int s_) {
        const int cpar = s_ & 1;                         // store made at end of step s_-1
        dual_store(hdP[cpar], myLo[cpar], myHi[cpar]);
        if (s_ >= 2) dual_store(hdP[cpar ^ 1], myLo[cpar ^ 1], myHi[cpar ^ 1]);
    };

    const u16* xwD = xw + (size_t)dir * TT * 8 * BB * 128;
    u64 pxw[4];
    int ptok;
    {
        const u16* p = xwD + (((size_t)0 * 8 + ug) * BB + cb) * 128 + cj * 4;
#pragma unroll
        for (int g = 0; g < 4; g++)
            pxw[g] = *reinterpret_cast<const u64*>(p + g * 32);
        ptok = tokens[cb * TT + (dir ? (TT - 1) : 0)];
    }

    float* outs_h = out + (size_t)BB * TT * 512;
    float* outs_c = outs_h + (size_t)BB * 512;

    bool sc0mode = true;
    int  sc0fail = 0;

    for (int s = 0; s < TT; s++) {
        const int p = s & 1;
        f32x4 acc[2][2];
#pragma unroll
        for (int mt = 0; mt < 2; mt++)
#pragma unroll
            for (int nt = 0; nt < 2; nt++) acc[mt][nt] = (f32x4){0.f, 0.f, 0.f, 0.f};

        u64 ql[16];
        if (s > 0) {
            const u32 tg = (tagbase + (u32)s) & 0xFFFFu;
            const u64 tp = (u64)tg | ((u64)tg << 32);
            const u64* hb = hgq + (size_t)(p * 2 + dir) * 4096 + wv * 1024 + l;
            bool ok = false;
            if (sc0mode) {
                u64 hb_u = (u64)(hgq + (size_t)(p * 2 + dir) * 4096 + wv * 1024);
                u32 blo = __builtin_amdgcn_readfirstlane((u32)hb_u);
                u32 bhi = __builtin_amdgcn_readfirstlane((u32)(hb_u >> 32));
                u64 hbs = ((u64)bhi << 32) | blo;
                const u32 vo = (u32)(l << 3);
                for (int r = 0; r < 12; ++r) {
                    poll16_l2(hbs, vo, ql);
                    u64 bad = 0;
#pragma unroll
                    for (int j = 0; j < 16; j++) bad |= ql[j] ^ tp;
                    if (__all((bad & TAGMASK) == 0ull)) { ok = true; break; }
                    __builtin_amdgcn_s_sleep(1);
                    if (r == 5) restoreMine(s);
                }
            }
            if (!ok) {
                if (sc0mode && ++sc0fail >= 3) sc0mode = false;   // sticky: degrade to r0 path
                int rr = 0;
                for (;;) {
#pragma unroll
                    for (int j = 0; j < 16; j++) ql[j] = ld_agent(hb + j * 64);
                    u64 bad = 0;
#pragma unroll
                    for (int j = 0; j < 16; j++) bad |= ql[j] ^ tp;
                    if (__all((bad & TAGMASK) == 0ull)) break;
                    __builtin_amdgcn_s_sleep(1);
                    if (((++rr) & 7) == 0) restoreMine(s);
                }
            } else {
                sc0fail = 0;
            }
        }

        // ---- prefetch next-step xw/token EARLY (nt: keep the XCD L2 clean) ----
        u64 pxw2[4]; int ptok2 = 0;
        if (s + 1 < TT) {
            const u16* px = xwD + (((size_t)(s + 1) * 8 + ug) * BB + cb) * 128 + cj * 4;
#pragma unroll
            for (int g = 0; g < 4; g++)
                pxw2[g] = __builtin_nontemporal_load(reinterpret_cast<const u64*>(px + g * 32));
            ptok2 = tokens[cb * TT + (dir ? (TT - 2 - s) : (s + 1))];
        }

        if (s > 0) {
            // ---- unpack to LDS: idx = wv*1024 + j*64 + l -> (ug_src, b, pos) ----
#pragma unroll
            for (int j = 0; j < 16; j++) {
                u32 w32 = (((u32)(ql[j] >> 16)) & 0xFFFFu) | (((u32)(ql[j] >> 48)) << 16);
                int ugs = wv * 2 + (j >> 3);
                int b   = (j * 4 + (l >> 4)) & 31;
                int pos = l & 15;
                int g   = ugs * 4 + (pos >> 2);
                HsW[b * 128 + ((g ^ (b & 7)) << 2) + (pos & 3)] = w32;
            }
            __syncthreads();   // (A) Hs visible to all waves

            // ---- A-fragments from LDS (swizzled, conflict-free) + MFMA ----
#pragma unroll
            for (int kt = 0; kt < 8; kt++) {
#pragma unroll
                for (int mt = 0; mt < 2; mt++) {
                    int b = mt * 16 + (l & 15);
                    int g = kt * 4 + (l >> 4);
                    short8 af = *reinterpret_cast<const short8*>(
                        &HsW[b * 128 + ((g ^ (b & 7)) << 2)]);
                    acc[mt][0] = __builtin_amdgcn_mfma_f32_16x16x32_bf16(af, bfrag[kt][0], acc[mt][0], 0, 0, 0);
                    acc[mt][1] = __builtin_amdgcn_mfma_f32_16x16x32_bf16(af, bfrag[kt][1], acc[mt][1], 0, 0, 0);
                }
            }
        }

        // scatter z into Zs[p]
#pragma unroll
        for (int mt = 0; mt < 2; mt++)
#pragma unroll
            for (int nt = 0; nt < 2; nt++)
#pragma unroll
                for (int r = 0; r < 4; r++)
                    Zs[p][mt * 16 + (l >> 4) * 4 + r][wv * 32 + nt * 16 + (l & 15)] = acc[mt][nt][r];
        __syncthreads();   // (B) Zs visible; also orders Hs-write(s+1) after afrag-read(s)

        // cell update: 4 units per thread
        float h2[4], c2[4];
        {
            const bool m = (ptok != 0);
#pragma unroll
            for (int q = 0; q < 4; q++) {
                float zi = Zs[p][cb][0 * 32 + cj * 4 + q] + bf2f((u16)(pxw[0] >> (16 * q)));
                float zf = Zs[p][cb][1 * 32 + cj * 4 + q] + bf2f((u16)(pxw[1] >> (16 * q)));
                float zg = Zs[p][cb][2 * 32 + cj * 4 + q] + bf2f((u16)(pxw[2] >> (16 * q)));
                float zo = Zs[p][cb][3 * 32 + cj * 4 + q] + bf2f((u16)(pxw[3] >> (16 * q)));
                float ii = 1.f / (1.f + __expf(-zi));
                float ff = 1.f / (1.f + __expf(-zf));
                float gg = fmaxf(zg, 0.f);
                float oo = 1.f / (1.f + __expf(-zo));
                float cn = ff * c_st[q] + ii * gg;
                float hn = oo * fmaxf(cn, 0.f);
                h2[q] = m ? hn : h_st[q];
                c2[q] = m ? cn : c_st[q];
                h_st[q] = h2[q];
                c_st[q] = c2[q];
            }
        }

        // h-store FIRST (critical path): dual-path tagged store (sc0 L2 + agent memory-side)
        {
            const u32 tagn = (tagbase + (u32)(s + 1)) & 0xFFFFu;
            u32 t0 = ((u32)f2bf(h2[0]) << 16) | tagn;
            u32 t1 = ((u32)f2bf(h2[1]) << 16) | tagn;
            u32 t2 = ((u32)f2bf(h2[2]) << 16) | tagn;
            u32 t3 = ((u32)f2bf(h2[3]) << 16) | tagn;
            u64 lo = (u64)t0 | ((u64)t1 << 32);
            u64 hi = (u64)t2 | ((u64)t3 << 32);
            const int par = (s + 1) & 1;
            dual_store(hdP[par], lo, hi);
            myLo[par] = lo; myHi[par] = hi;
        }

        // off-critical-path: out stores (nt: keep XCD L2 clean), final states
        const int tv = dir ? (TT - 1 - s) : s;
        {
            f32x4 ov = (f32x4){h2[0], h2[1], h2[2], h2[3]};
            __builtin_nontemporal_store(ov,
                reinterpret_cast<f32x4*>(&out[((size_t)cb * TT + tv) * 512 + dir * UU + unit0 + cj * 4]));
        }
        if (s == TT - 1) {
            if (dir == 0) {
                *reinterpret_cast<f32x4*>(&outs_h[cb * 512 + unit0 + cj * 4]) = (f32x4){h2[0], h2[1], h2[2], h2[3]};
                *reinterpret_cast<f32x4*>(&outs_c[cb * 512 + unit0 + cj * 4]) = (f32x4){c2[0], c2[1], c2[2], c2[3]};
            } else {
                // ref: state_h = concat(hf, cb); state_c = concat(cf, cb)
                *reinterpret_cast<f32x4*>(&outs_h[cb * 512 + UU + unit0 + cj * 4]) = (f32x4){c2[0], c2[1], c2[2], c2[3]};
                *reinterpret_cast<f32x4*>(&outs_c[cb * 512 + UU + unit0 + cj * 4]) = (f32x4){c2[0], c2[1], c2[2], c2[3]};
            }
        }
        if (s + 1 < TT) {
#pragma unroll
            for (int g = 0; g < 4; g++) pxw[g] = pxw2[g];
            ptok = ptok2;
        }
        // NO loop-end barrier: Zs is parity-buffered; barrier (B) of step s orders every
        // thread's afrag/Zs reads of step s before any thread's step-s+1 LDS writes.
    }
}

extern "C" void kernel_launch(void* const* d_in, const int* in_sizes, int n_in,
                              void* d_out, int out_size, void* d_ws, size_t ws_size,
                              hipStream_t stream) {
    const int*   tokens = (const int*)d_in[0];
    const float* emb    = (const float*)d_in[1];
    const float* Wk_f   = (const float*)d_in[2];
    const float* Wr_f   = (const float*)d_in[3];
    const float* b_f    = (const float*)d_in[4];
    const float* Wk_b   = (const float*)d_in[5];
    const float* Wr_b   = (const float*)d_in[6];
    const float* b_b    = (const float*)d_in[7];
    float* out = (float*)d_out;

    char* ws = (char*)d_ws;
    u16* xw  = (u16*)ws;                       // 67,108,864 B
    u64* hgq = (u64*)(ws + 67108864);          // 262,144 B (tagged u32 h; NOT memset — epoch
                                               // tags make stale/garbage unmatchable)

    // claim-control block in the last 64 B of d_out (state_c tail, overwritten by the
    // workers' final stores at s=T-1, long after claiming finishes).
    char* ctl = (char*)d_out + (size_t)out_size - 64;

    (void)hipMemsetAsync(ctl, 0xFF, 12, stream);     // w0 = w1 = epoch = -1
    (void)hipMemsetAsync(ctl + 16, 0, 32, stream);   // cnt[8] = 0
    dim3 g1(8, 256, 2);
    xw_gemm<<<g1, 256, 0, stream>>>(tokens, emb, Wk_f, b_f, Wk_b, b_b, xw);
    lstm_rec<<<128, 256, 0, stream>>>(tokens, xw, Wr_f, Wr_b, hgq, (int*)ctl, out);
}

// Round 4
// 1761.140 us; speedup vs baseline: 1.8940x; 1.8940x over previous
//
#include <hip/hip_runtime.h>
#include <hip/hip_bf16.h>

#define TT 512
#define BB 32
#define EE 256
#define UU 256
#define NG 1024   // 4*U
#define SHW 16384 // shadow offset in u64 (128 KB)

typedef unsigned int u32;
typedef unsigned long long u64;
typedef unsigned short u16;
typedef __attribute__((ext_vector_type(8))) short short8;   // 8 bf16 (4 VGPRs)
typedef __attribute__((ext_vector_type(4))) float f32x4;
typedef __attribute__((ext_vector_type(4))) u32 u32x4;

#define TAGMASK 0x0000FFFF0000FFFFull

__device__ __forceinline__ float bf2f(u16 u) { return __uint_as_float(((u32)u) << 16); }
__device__ __forceinline__ u16 f2bf(float f) {
    u32 x = __float_as_uint(f);
    u32 r = (x + 0x7fffu + ((x >> 16) & 1u)) >> 16;   // RNE
    return (u16)r;
}

// ---------------- Phase 1: xw2[dir][t'][ug][b][128] = (emb[tokens] @ Wk + bias), bf16 ----
__launch_bounds__(256)
__global__ void xw_gemm(const int* __restrict__ tokens,
                        const float* __restrict__ emb,
                        const float* __restrict__ Wk_f, const float* __restrict__ b_f,
                        const float* __restrict__ Wk_b, const float* __restrict__ b_b,
                        u16* __restrict__ xw)
{
    const int dir = blockIdx.z;
    const float* Wk   = dir ? Wk_b : Wk_f;
    const float* bias = dir ? b_b  : b_f;
    const int bn = blockIdx.x;   // 8 tiles of 128 cols
    const int bm = blockIdx.y;   // 256 tiles of 64 rows
    const int tid = threadIdx.x;

    __shared__ __align__(16) float At[32][68];
    __shared__ __align__(16) float Bs[32][132];

    float acc[8][4];
#pragma unroll
    for (int i = 0; i < 8; i++)
#pragma unroll
        for (int j = 0; j < 4; j++) acc[i][j] = 0.f;

    const int tx = tid & 31;
    const int ty = tid >> 5;
    const int c0 = tx * 4;
    const int r0 = ty * 8;

    const int lr = tid >> 3;
    const int lk = (tid & 7) * 4;

    for (int k0 = 0; k0 < EE; k0 += 32) {
#pragma unroll
        for (int p = 0; p < 2; p++) {
            int r = lr + p * 32;
            int row = bm * 64 + r;
            int tok = tokens[row];
            const float4 v = *reinterpret_cast<const float4*>(&emb[(size_t)tok * EE + k0 + lk]);
            At[lk + 0][r] = v.x; At[lk + 1][r] = v.y; At[lk + 2][r] = v.z; At[lk + 3][r] = v.w;
        }
        {
            int ck = (tid & 31) * 4;
            int kk = tid >> 5;
#pragma unroll
            for (int p = 0; p < 4; p++) {
                int k = kk + p * 8;
                const float4 v = *reinterpret_cast<const float4*>(&Wk[(size_t)(k0 + k) * NG + bn * 128 + ck]);
                *reinterpret_cast<float4*>(&Bs[k][ck]) = v;
            }
        }
        __syncthreads();
#pragma unroll 8
        for (int k = 0; k < 32; k++) {
            float4 a0 = *reinterpret_cast<const float4*>(&At[k][r0]);
            float4 a1 = *reinterpret_cast<const float4*>(&At[k][r0 + 4]);
            float4 b0 = *reinterpret_cast<const float4*>(&Bs[k][c0]);
            float a[8] = {a0.x, a0.y, a0.z, a0.w, a1.x, a1.y, a1.z, a1.w};
            float b[4] = {b0.x, b0.y, b0.z, b0.w};
#pragma unroll
            for (int i = 0; i < 8; i++)
#pragma unroll
                for (int j = 0; j < 4; j++)
                    acc[i][j] = fmaf(a[i], b[j], acc[i][j]);
        }
        __syncthreads();
    }

    float4 bv = *reinterpret_cast<const float4*>(&bias[bn * 128 + c0]);
    float bias4[4] = {bv.x, bv.y, bv.z, bv.w};
    const int cbase = bn * 128 + c0;
    const int gate  = cbase >> 8;
    const int unitv = cbase & 255;
    const int ugx   = unitv >> 5;
    const int wcol  = gate * 32 + (unitv & 31);
#pragma unroll
    for (int i = 0; i < 8; i++) {
        int row = bm * 64 + r0 + i;
        int b = row >> 9;
        int t = row & 511;
        int t2 = dir ? (TT - 1 - t) : t;
        size_t base = ((((size_t)(dir * TT + t2)) * 8 + ugx) * BB + b) * 128 + wcol;
        ushort4 st;
        st.x = f2bf(acc[i][0] + bias4[0]);
        st.y = f2bf(acc[i][1] + bias4[1]);
        st.z = f2bf(acc[i][2] + bias4[2]);
        st.w = f2bf(acc[i][3] + bias4[3]);
        *reinterpret_cast<ushort4*>(&xw[base]) = st;
    }
}

__device__ __forceinline__ u64 ld_agent(const u64* p) {
    return __hip_atomic_load(p, __ATOMIC_RELAXED, __HIP_MEMORY_SCOPE_AGENT);
}

// ---- sc0 16x dwordx2 load, issue only (NO waitcnt) — used for drain-free early poll ----
__device__ __forceinline__ void poll16_issue(u64 b0, u32 voff, u64* q) {
    asm volatile(
        "global_load_dwordx2 %[q0], %[vo], %[b0] sc0\n\t"
        "global_load_dwordx2 %[q1], %[vo], %[b0] offset:512 sc0\n\t"
        "global_load_dwordx2 %[q2], %[vo], %[b0] offset:1024 sc0\n\t"
        "global_load_dwordx2 %[q3], %[vo], %[b0] offset:1536 sc0\n\t"
        "global_load_dwordx2 %[q4], %[vo], %[b0] offset:2048 sc0\n\t"
        "global_load_dwordx2 %[q5], %[vo], %[b0] offset:2560 sc0\n\t"
        "global_load_dwordx2 %[q6], %[vo], %[b0] offset:3072 sc0\n\t"
        "global_load_dwordx2 %[q7], %[vo], %[b0] offset:3584 sc0\n\t"
        "global_load_dwordx2 %[q8], %[vo], %[b1] sc0\n\t"
        "global_load_dwordx2 %[q9], %[vo], %[b1] offset:512 sc0\n\t"
        "global_load_dwordx2 %[q10], %[vo], %[b1] offset:1024 sc0\n\t"
        "global_load_dwordx2 %[q11], %[vo], %[b1] offset:1536 sc0\n\t"
        "global_load_dwordx2 %[q12], %[vo], %[b1] offset:2048 sc0\n\t"
        "global_load_dwordx2 %[q13], %[vo], %[b1] offset:2560 sc0\n\t"
        "global_load_dwordx2 %[q14], %[vo], %[b1] offset:3072 sc0\n\t"
        "global_load_dwordx2 %[q15], %[vo], %[b1] offset:3584 sc0"
        : [q0]"=&v"(q[0]), [q1]"=&v"(q[1]), [q2]"=&v"(q[2]), [q3]"=&v"(q[3]),
          [q4]"=&v"(q[4]), [q5]"=&v"(q[5]), [q6]"=&v"(q[6]), [q7]"=&v"(q[7]),
          [q8]"=&v"(q[8]), [q9]"=&v"(q[9]), [q10]"=&v"(q[10]), [q11]"=&v"(q[11]),
          [q12]"=&v"(q[12]), [q13]"=&v"(q[13]), [q14]"=&v"(q[14]), [q15]"=&v"(q[15])
        : [vo]"v"(voff), [b0]"s"(b0), [b1]"s"(b0 + 4096ull)
        : "memory");
}

// ---- sc0 16x dwordx2 poll with full drain (slow-path rounds) ----
__device__ __forceinline__ void poll16_l2(u64 b0, u32 voff, u64* q) {
    poll16_issue(b0, voff, q);
    asm volatile("s_waitcnt vmcnt(0)"
        : "+v"(q[0]), "+v"(q[1]), "+v"(q[2]), "+v"(q[3]),
          "+v"(q[4]), "+v"(q[5]), "+v"(q[6]), "+v"(q[7]),
          "+v"(q[8]), "+v"(q[9]), "+v"(q[10]), "+v"(q[11]),
          "+v"(q[12]), "+v"(q[13]), "+v"(q[14]), "+v"(q[15]));
}

// sc0 dwordx4 store into this XCD's L2 (the ONLY writer of the primary spun lines)
__device__ __forceinline__ void st16_l2(u64* addr, u64 lo, u64 hi) {
    u32x4 v = (u32x4){(u32)lo, (u32)(lo >> 32), (u32)hi, (u32)(hi >> 32)};
    asm volatile("global_store_dwordx4 %[a], %[d], off sc0"
                 :: [a]"v"(addr), [d]"v"(v) : "memory");
}

// ---------------- Phase 2: persistent recurrence, 16 worker WGs clustered on <=2 XCDs ----
// Claiming as r3 (verified working: FETCH showed polls L2-resident). Exchange redesign:
// primary buffer is sc0-ONLY (consumers spin on it; single writer path -> no sc1 line
// poisoning). A SHADOW buffer 128KB away gets relaxed agent stores each step (posted,
// off critical path, different cache lines). Fallback consumers poll the shadow;
// restoreMine dual-writes both. Fail-to-slow preserved; fast path now clean.
__launch_bounds__(256, 1)
__global__ void lstm_rec(const int* __restrict__ tokens,
                         const u16* __restrict__ xw,     // [dir][t][ug][b][128]
                         const float* __restrict__ Wr_f,
                         const float* __restrict__ Wr_b,
                         u64* __restrict__ hgq,          // primary 128KB + shadow 128KB
                         int* __restrict__ ctl,          // [w0,w1,epoch,pad, cnt[8]] in d_out tail
                         float* __restrict__ out)
{
    const int tid = threadIdx.x;

    __shared__ int s_role, s_epoch;
    __shared__ __align__(16) u32   HsW[32 * 128];   // h as bf16 pairs, swizzled granules (16 KB)
    __shared__ __align__(16) float Zs[2][BB][132];  // parity-buffered z (33.8 KB)

    // ---- XCD claiming (cannot hang: pigeonhole over 128 co-resident WGs sets w0,w1) ----
    if (tid == 0) {
        u32 xcc;
        asm volatile("s_getreg_b32 %0, hwreg(HW_REG_XCC_ID)" : "=s"(xcc));
        xcc &= 7u;
        u32* cnt = (u32*)(ctl + 4);
        u32 slot = atomicAdd(&cnt[xcc], 1u);
        if (slot == 7u) {
            if (atomicCAS(&ctl[0], -1, (int)xcc) == -1) {
                u64 rt = __builtin_amdgcn_s_memrealtime();
                int ep = (int)((((u32)rt ^ (u32)(rt >> 32)) & 0x7FFFFFFEu) | 1u);  // != -1
                atomicExch(&ctl[2], ep);
            } else {
                atomicCAS(&ctl[1], -1, (int)xcc);
            }
        } else if (slot == 15u) {
            atomicCAS(&ctl[1], -1, (int)xcc);
        }
        int w0, w1, ep;
        for (;;) {
            w0 = __hip_atomic_load(&ctl[0], __ATOMIC_RELAXED, __HIP_MEMORY_SCOPE_AGENT);
            w1 = __hip_atomic_load(&ctl[1], __ATOMIC_RELAXED, __HIP_MEMORY_SCOPE_AGENT);
            ep = __hip_atomic_load(&ctl[2], __ATOMIC_RELAXED, __HIP_MEMORY_SCOPE_AGENT);
            if (w0 >= 0 && w1 >= 0 && ep != -1) break;
            __builtin_amdgcn_s_sleep(8);
        }
        int role = -1;
        if ((int)xcc == w0 && slot < 8u) role = (int)slot;                                 // dir 0
        else if (w1 == w0 && (int)xcc == w0 && slot >= 8u && slot < 16u) role = (int)slot; // dir 1 (same XCD)
        else if (w1 != w0 && (int)xcc == w1 && slot < 8u) role = 8 + (int)slot;            // dir 1
        s_role = role;
        s_epoch = ep;
    }
    __syncthreads();
    const int role = s_role;
    const u32 tagbase = (u32)s_epoch * 2654435761u;
    if (role < 0) return;

    const int dir = role >> 3;
    const int ug  = role & 7;
    const int unit0 = ug * 32;
    const int wv  = tid >> 6;        // wave = gate
    const int l   = tid & 63;

    // ---- load Wr B-fragments (bf16) into registers, once ----
    const float* Wr = dir ? Wr_b : Wr_f;
    short8 bfrag[8][2];
    {
        const int col = wv * UU + unit0 + (l & 15);
#pragma unroll
        for (int kt = 0; kt < 8; kt++) {
#pragma unroll
            for (int nt = 0; nt < 2; nt++) {
                int k0 = kt * 32 + (l >> 4) * 8;
                short8 v;
#pragma unroll
                for (int jj = 0; jj < 8; jj++)
                    v[jj] = (short)f2bf(Wr[(size_t)(k0 + jj) * NG + col + nt * 16]);
                bfrag[kt][nt] = v;
            }
        }
    }

    const int cb = tid >> 3;
    const int cj = tid & 7;
    float c_st[4] = {0.f, 0.f, 0.f, 0.f};
    float h_st[4] = {0.f, 0.f, 0.f, 0.f};

    // my exchange slots, both parities; primary (sc0-only) + shadow (agent-only)
    u64* const hdP[2] = {
        hgq + (size_t)(0 * 2 + dir) * 4096 + (ug * 32 + cb) * 16 + cj * 2,
        hgq + (size_t)(1 * 2 + dir) * 4096 + (ug * 32 + cb) * 16 + cj * 2
    };
    u64* const shP[2] = { hdP[0] + SHW, hdP[1] + SHW };
    u64 myLo[2] = {0ull, 0ull}, myHi[2] = {0ull, 0ull};

    // re-store my last two tagged payloads on BOTH paths (liveness repair; skew<=1)
    auto restoreMine = [&](int s_) {
        const int cpar = s_ & 1;                         // store made at end of step s_-1
        st16_l2(hdP[cpar], myLo[cpar], myHi[cpar]);
        __hip_atomic_store(shP[cpar] + 0, myLo[cpar], __ATOMIC_RELAXED, __HIP_MEMORY_SCOPE_AGENT);
        __hip_atomic_store(shP[cpar] + 1, myHi[cpar], __ATOMIC_RELAXED, __HIP_MEMORY_SCOPE_AGENT);
        if (s_ >= 2) {
            st16_l2(hdP[cpar ^ 1], myLo[cpar ^ 1], myHi[cpar ^ 1]);
            __hip_atomic_store(shP[cpar ^ 1] + 0, myLo[cpar ^ 1], __ATOMIC_RELAXED, __HIP_MEMORY_SCOPE_AGENT);
            __hip_atomic_store(shP[cpar ^ 1] + 1, myHi[cpar ^ 1], __ATOMIC_RELAXED, __HIP_MEMORY_SCOPE_AGENT);
        }
    };

    const u16* xwD = xw + (size_t)dir * TT * 8 * BB * 128;
    u64 pxw[4];
    int ptok;
    {
        const u16* p = xwD + (((size_t)0 * 8 + ug) * BB + cb) * 128 + cj * 4;
#pragma unroll
        for (int g = 0; g < 4; g++)
            pxw[g] = *reinterpret_cast<const u64*>(p + g * 32);
        ptok = tokens[cb * TT + (dir ? (TT - 1) : 0)];
    }

    float* outs_h = out + (size_t)BB * TT * 512;
    float* outs_c = outs_h + (size_t)BB * 512;

    bool sc0mode = true;
    int  sc0fail = 0;
    u64  ql[16];
    const u32 vo = (u32)(l << 3);

    for (int s = 0; s < TT; s++) {
        const int p = s & 1;
        f32x4 acc[2][2];
#pragma unroll
        for (int mt = 0; mt < 2; mt++)
#pragma unroll
            for (int nt = 0; nt < 2; nt++) acc[mt][nt] = (f32x4){0.f, 0.f, 0.f, 0.f};

        if (s > 0) {
            const u32 tg = (tagbase + (u32)s) & 0xFFFFu;
            const u64 tp = (u64)tg | ((u64)tg << 32);
            u64 region = (size_t)(p * 2 + dir) * 4096 + wv * 1024;
            bool good = false;
            if (sc0mode) {
                // early-issued loads from end of step s-1: wait exactly h-store + 16 polls
                asm volatile("s_waitcnt vmcnt(8)"
                    : "+v"(ql[0]), "+v"(ql[1]), "+v"(ql[2]), "+v"(ql[3]),
                      "+v"(ql[4]), "+v"(ql[5]), "+v"(ql[6]), "+v"(ql[7]),
                      "+v"(ql[8]), "+v"(ql[9]), "+v"(ql[10]), "+v"(ql[11]),
                      "+v"(ql[12]), "+v"(ql[13]), "+v"(ql[14]), "+v"(ql[15]));
                u64 bad = 0;
#pragma unroll
                for (int j = 0; j < 16; j++) bad |= ql[j] ^ tp;
                good = __all((bad & TAGMASK) == 0ull);
                if (!good) {
                    // bounded sc0 re-poll
                    u64 hb_u = (u64)(hgq + region);
                    u32 blo = __builtin_amdgcn_readfirstlane((u32)hb_u);
                    u32 bhi = __builtin_amdgcn_readfirstlane((u32)(hb_u >> 32));
                    u64 hbs = ((u64)bhi << 32) | blo;
                    for (int r = 0; r < 6; ++r) {
                        poll16_l2(hbs, vo, ql);
                        u64 b2 = 0;
#pragma unroll
                        for (int j = 0; j < 16; j++) b2 |= ql[j] ^ tp;
                        if (__all((b2 & TAGMASK) == 0ull)) { good = true; break; }
                        __builtin_amdgcn_s_sleep(1);
                        if (r == 2) restoreMine(s);
                    }
                }
            }
            if (good) {
                sc0fail = 0;
            } else {
                if (sc0mode && ++sc0fail >= 3) sc0mode = false;   // sticky: shadow-only
                const u64* hb_sh = hgq + SHW + region + l;
                int rr = 0;
                for (;;) {
#pragma unroll
                    for (int j = 0; j < 16; j++) ql[j] = ld_agent(hb_sh + j * 64);
                    u64 b2 = 0;
#pragma unroll
                    for (int j = 0; j < 16; j++) b2 |= ql[j] ^ tp;
                    if (__all((b2 & TAGMASK) == 0ull)) break;
                    __builtin_amdgcn_s_sleep(1);
                    if (((++rr) & 7) == 0) restoreMine(s);
                }
            }

            // ---- unpack to LDS: idx = wv*1024 + j*64 + l -> (ug_src, b, pos) ----
#pragma unroll
            for (int j = 0; j < 16; j++) {
                u32 w32 = (((u32)(ql[j] >> 16)) & 0xFFFFu) | (((u32)(ql[j] >> 48)) << 16);
                int ugs = wv * 2 + (j >> 3);
                int b   = (j * 4 + (l >> 4)) & 31;
                int pos = l & 15;
                int g   = ugs * 4 + (pos >> 2);
                HsW[b * 128 + ((g ^ (b & 7)) << 2) + (pos & 3)] = w32;
            }
            __syncthreads();   // (A) Hs visible to all waves

            // ---- A-fragments from LDS (swizzled, conflict-free) + MFMA ----
#pragma unroll
            for (int kt = 0; kt < 8; kt++) {
#pragma unroll
                for (int mt = 0; mt < 2; mt++) {
                    int b = mt * 16 + (l & 15);
                    int g = kt * 4 + (l >> 4);
                    short8 af = *reinterpret_cast<const short8*>(
                        &HsW[b * 128 + ((g ^ (b & 7)) << 2)]);
                    acc[mt][0] = __builtin_amdgcn_mfma_f32_16x16x32_bf16(af, bfrag[kt][0], acc[mt][0], 0, 0, 0);
                    acc[mt][1] = __builtin_amdgcn_mfma_f32_16x16x32_bf16(af, bfrag[kt][1], acc[mt][1], 0, 0, 0);
                }
            }
        }

        // scatter z into Zs[p]
#pragma unroll
        for (int mt = 0; mt < 2; mt++)
#pragma unroll
            for (int nt = 0; nt < 2; nt++)
#pragma unroll
                for (int r = 0; r < 4; r++)
                    Zs[p][mt * 16 + (l >> 4) * 4 + r][wv * 32 + nt * 16 + (l & 15)] = acc[mt][nt][r];
        __syncthreads();   // (B) Zs visible; also orders Hs-write(s+1) after afrag-read(s)

        // cell update: 4 units per thread
        float h2[4], c2[4];
        {
            const bool m = (ptok != 0);
#pragma unroll
            for (int q = 0; q < 4; q++) {
                float zi = Zs[p][cb][0 * 32 + cj * 4 + q] + bf2f((u16)(pxw[0] >> (16 * q)));
                float zf = Zs[p][cb][1 * 32 + cj * 4 + q] + bf2f((u16)(pxw[1] >> (16 * q)));
                float zg = Zs[p][cb][2 * 32 + cj * 4 + q] + bf2f((u16)(pxw[2] >> (16 * q)));
                float zo = Zs[p][cb][3 * 32 + cj * 4 + q] + bf2f((u16)(pxw[3] >> (16 * q)));
                float ii = 1.f / (1.f + __expf(-zi));
                float ff = 1.f / (1.f + __expf(-zf));
                float gg = fmaxf(zg, 0.f);
                float oo = 1.f / (1.f + __expf(-zo));
                float cn = ff * c_st[q] + ii * gg;
                float hn = oo * fmaxf(cn, 0.f);
                h2[q] = m ? hn : h_st[q];
                c2[q] = m ? cn : c_st[q];
                h_st[q] = h2[q];
                c_st[q] = c2[q];
            }
        }

        // ---- critical path: single sc0 h-store to primary ----
        const int par = (s + 1) & 1;
        {
            const u32 tagn = (tagbase + (u32)(s + 1)) & 0xFFFFu;
            u32 t0 = ((u32)f2bf(h2[0]) << 16) | tagn;
            u32 t1 = ((u32)f2bf(h2[1]) << 16) | tagn;
            u32 t2 = ((u32)f2bf(h2[2]) << 16) | tagn;
            u32 t3 = ((u32)f2bf(h2[3]) << 16) | tagn;
            u64 lo = (u64)t0 | ((u64)t1 << 32);
            u64 hi = (u64)t2 | ((u64)t3 << 32);
            st16_l2(hdP[par], lo, hi);
            myLo[par] = lo; myHi[par] = hi;
        }

        // ---- drain-free early poll issue for step s+1 (16 loads, no wait) ----
        if (s + 1 < TT && sc0mode) {
            u64 nregion = (size_t)(((s + 1) & 1) * 2 + dir) * 4096 + wv * 1024;
            u64 hb_u = (u64)(hgq + nregion);
            u32 blo = __builtin_amdgcn_readfirstlane((u32)hb_u);
            u32 bhi = __builtin_amdgcn_readfirstlane((u32)(hb_u >> 32));
            u64 hbs = ((u64)bhi << 32) | blo;
            poll16_issue(hbs, vo, ql);
        }

        // ---- posted, off-critical-path: shadow agent copy (different cache lines) ----
        __hip_atomic_store(shP[par] + 0, myLo[par], __ATOMIC_RELAXED, __HIP_MEMORY_SCOPE_AGENT);
        __hip_atomic_store(shP[par] + 1, myHi[par], __ATOMIC_RELAXED, __HIP_MEMORY_SCOPE_AGENT);

        // out store (nt: keep XCD L2 clean), final states
        const int tv = dir ? (TT - 1 - s) : s;
        {
            f32x4 ov = (f32x4){h2[0], h2[1], h2[2], h2[3]};
            __builtin_nontemporal_store(ov,
                reinterpret_cast<f32x4*>(&out[((size_t)cb * TT + tv) * 512 + dir * UU + unit0 + cj * 4]));
        }
        if (s == TT - 1) {
            if (dir == 0) {
                *reinterpret_cast<f32x4*>(&outs_h[cb * 512 + unit0 + cj * 4]) = (f32x4){h2[0], h2[1], h2[2], h2[3]};
                *reinterpret_cast<f32x4*>(&outs_c[cb * 512 + unit0 + cj * 4]) = (f32x4){c2[0], c2[1], c2[2], c2[3]};
            } else {
                // ref: state_h = concat(hf, cb); state_c = concat(cf, cb)
                *reinterpret_cast<f32x4*>(&outs_h[cb * 512 + UU + unit0 + cj * 4]) = (f32x4){c2[0], c2[1], c2[2], c2[3]};
                *reinterpret_cast<f32x4*>(&outs_c[cb * 512 + UU + unit0 + cj * 4]) = (f32x4){c2[0], c2[1], c2[2], c2[3]};
            }
        }
        // ---- prefetch next xw/token DIRECTLY into pxw/ptok (no copy -> no back-edge wait;
        //      compiler's vmcnt lands at next cell update, after the poll) ----
        if (s + 1 < TT) {
            const u16* px = xwD + (((size_t)(s + 1) * 8 + ug) * BB + cb) * 128 + cj * 4;
#pragma unroll
            for (int g = 0; g < 4; g++)
                pxw[g] = __builtin_nontemporal_load(reinterpret_cast<const u64*>(px + g * 32));
            ptok = tokens[cb * TT + (dir ? (TT - 2 - s) : (s + 1))];
        }
        // NO loop-end barrier: Zs is parity-buffered; barrier (B) of step s orders every
        // thread's afrag/Zs reads of step s before any thread's step-s+1 LDS writes.
    }
}

extern "C" void kernel_launch(void* const* d_in, const int* in_sizes, int n_in,
                              void* d_out, int out_size, void* d_ws, size_t ws_size,
                              hipStream_t stream) {
    const int*   tokens = (const int*)d_in[0];
    const float* emb    = (const float*)d_in[1];
    const float* Wk_f   = (const float*)d_in[2];
    const float* Wr_f   = (const float*)d_in[3];
    const float* b_f    = (const float*)d_in[4];
    const float* Wk_b   = (const float*)d_in[5];
    const float* Wr_b   = (const float*)d_in[6];
    const float* b_b    = (const float*)d_in[7];
    float* out = (float*)d_out;

    char* ws = (char*)d_ws;
    u16* xw  = (u16*)ws;                       // 67,108,864 B
    u64* hgq = (u64*)(ws + 67108864);          // 262,144 B: primary 128KB (sc0-only) +
                                               // shadow 128KB (agent-only). NOT memset —
                                               // epoch tags make stale/garbage unmatchable.

    // claim-control block in the last 64 B of d_out (state_c tail, overwritten by the
    // workers' final stores at s=T-1, long after claiming finishes).
    char* ctl = (char*)d_out + (size_t)out_size - 64;

    (void)hipMemsetAsync(ctl, 0xFF, 12, stream);     // w0 = w1 = epoch = -1
    (void)hipMemsetAsync(ctl + 16, 0, 32, stream);   // cnt[8] = 0
    dim3 g1(8, 256, 2);
    xw_gemm<<<g1, 256, 0, stream>>>(tokens, emb, Wk_f, b_f, Wk_b, b_b, xw);
    lstm_rec<<<128, 256, 0, stream>>>(tokens, xw, Wr_f, Wr_b, hgq, (int*)ctl, out);
}